// Round 8
// baseline (589.164 us; speedup 1.0000x reference)
//
#include <hip/hip_runtime.h>
#include <hip/hip_bf16.h>

// HodgkinHuxley 7-state ODE scan: T=500 sequential steps, N=20000 neurons.
// Round 8: 4 neurons per thread (5000 threads, 79 waves). At 1 wave/SIMD the
// round-7 kernel was stall-bound (600 cy/step vs ~194 cy issue floor): all
// result latencies exposed, ~5 chains of ILP insufficient. 4 independent
// neurons per thread x-interleaved per step quadruples ILP -> issue-bound.
// Neuron k of thread n is (n + k*5000): all 4 load/store streams stay
// coalesced across the 64 consecutive lanes of a wave.
//
// Per-neuron math identical to round 7 (passed, absmax 0.25):
//  - sigmoid arg in ONE fma; sig = v_rcp(1 + v_exp2(arg))
//  - V = fma(num, kV, V) with num = t3 - gtot*V
//  - gate: r = fma(A_r, r, B_r*sig)

#define TSTEPS 500
#define NNEUR  20000
#define KN     4
#define NT     (NNEUR / KN)        /* 5000 threads */
#define DTS    0.1f
#define LOG2E  1.442695040888963f

__device__ __forceinline__ float hw_exp2(float x) { return __builtin_amdgcn_exp2f(x); }
__device__ __forceinline__ float hw_rcp(float x)  { return __builtin_amdgcn_rcpf(x); }

__global__ __launch_bounds__(64, 1)
void hh_kernel(const float* __restrict__ i_inj,
               const float* __restrict__ x0,
               const float* __restrict__ prm,
               float* __restrict__ out)
{
    const int n = blockIdx.x * 64 + threadIdx.x;
    if (n >= NT) return;

    // params (PNAMES order)
    const float decay_ca = prm[0],  rho_ca  = prm[1];
    const float p_tau = prm[2],  p_scale = prm[3],  p_mdp = prm[4];
    const float q_tau = prm[5],  q_scale = prm[6],  q_mdp = prm[7];
    const float n_tau = prm[8],  n_scale = prm[9],  n_mdp = prm[10];
    const float f_tau = prm[11], f_scale = prm[12], f_mdp = prm[13];
    const float e_tau = prm[14], e_scale = prm[15], e_mdp = prm[16];
    const float h_alpha = prm[17], h_scale = prm[18], h_mdp = prm[19];
    const float C_m = prm[20], g_Ca = prm[21], g_Ks = prm[22];
    const float g_Kf = prm[23], g_L = prm[24];
    const float E_Ca = prm[25], E_K = prm[26], E_L = prm[27];

    // ---- loop-invariant folded constants (uniform -> SGPRs) ----
    const float kV    = DTS / C_m;
    const float cLEL  = g_L * E_L;
    const float cKeep = 1.0f - DTS / decay_ca;
    const float cRho  = rho_ca * DTS;

    const float isH = 1.0f / h_scale;
    const float zaH = -LOG2E * isH, zbH = h_mdp * isH * LOG2E;
    const float aG  = h_alpha * g_Ca;
    const float bG  = (1.0f - h_alpha) * g_Ca;

#define GATECONST(r, tau, scale, mdp)                                          \
    const float cf_##r = (tau) * DTS / ((tau) + DTS);                          \
    const float A_##r  = cf_##r / DTS;                                         \
    const float B_##r  = cf_##r / (tau);                                       \
    const float za##r  = -LOG2E / (scale);                                     \
    const float zb##r  = (mdp) * LOG2E / (scale);
    GATECONST(p, p_tau, p_scale, p_mdp)
    GATECONST(q, q_tau, q_scale, q_mdp)
    GATECONST(n, n_tau, n_scale, n_mdp)
    GATECONST(f, f_tau, f_scale, f_mdp)
    GATECONST(e, e_tau, e_scale, e_mdp)
#undef GATECONST

    // ---- per-neuron state (static indexing only; fully unrolled) ----
    float V[KN], P[KN], Q[KN], NN[KN], E[KN], F[KN], C[KN];
#pragma unroll
    for (int k = 0; k < KN; ++k) {
        const int nk = n + k * NT;
        V[k]  = x0[0 * NNEUR + nk];
        P[k]  = x0[1 * NNEUR + nk];
        Q[k]  = x0[2 * NNEUR + nk];
        NN[k] = x0[3 * NNEUR + nk];
        E[k]  = x0[4 * NNEUR + nk];
        F[k]  = x0[5 * NNEUR + nk];
        C[k]  = x0[6 * NNEUR + nk];
    }

    // ---- stream bases + 32-bit byte offsets ----
    float* const oV = out + 0 * NNEUR;
    float* const oP = out + 1 * NNEUR;
    float* const oQ = out + 2 * NNEUR;
    float* const oN = out + 3 * NNEUR;
    float* const oE = out + 4 * NNEUR;
    float* const oF = out + 5 * NNEUR;
    float* const oC = out + 6 * NNEUR;

    const unsigned ISTEP = (unsigned)NNEUR * 4u;        // i_inj row stride
    const unsigned BSTEP = 7u * NNEUR * 4u;             // out step stride
    unsigned bo[KN];                                    // out byte offsets
    unsigned i0[KN];                                    // i_inj col base
#pragma unroll
    for (int k = 0; k < KN; ++k) {
        bo[k] = (unsigned)(n + k * NT) * 4u;
        i0[k] = (unsigned)(n + k * NT) * 4u;
    }

#define LD(off)      (*(const float*)((const char*)i_inj + (off)))
#define ST(ptr, off) (*(float*)((char*)(ptr) + (off)))

#define HH_STEP(k, cur)                                                        \
    {                                                                          \
        const float hs  = hw_rcp(1.0f + hw_exp2(fmaf(C[k], zaH, zbH)));        \
        const float hg  = fmaf(hs, aG, bG);                                    \
        const float geh = (E[k] * E[k]) * (F[k] * hg);                         \
        const float p2  = P[k] * P[k];                                         \
        const float g   = fmaf(g_Kf, (p2 * p2) * Q[k], g_Ks * NN[k]);          \
        const float gtot = geh + g + g_L;                                      \
        const float t3  = fmaf(g, E_K, fmaf(geh, E_Ca, (cur) + cLEL));         \
        const float num = fmaf(-gtot, V[k], t3);                               \
        V[k] = fmaf(num, kV, V[k]);                                            \
        const float ica2 = geh * (V[k] - E_Ca);                                \
        C[k] = fmaf(C[k], cKeep, -(ica2 * cRho));                              \
        const float sp = hw_rcp(1.0f + hw_exp2(fmaf(V[k], zap, zbp)));         \
        const float sq = hw_rcp(1.0f + hw_exp2(fmaf(V[k], zaq, zbq)));         \
        const float se = hw_rcp(1.0f + hw_exp2(fmaf(V[k], zae, zbe)));         \
        const float sf = hw_rcp(1.0f + hw_exp2(fmaf(V[k], zaf, zbf)));         \
        const float sn = hw_rcp(1.0f + hw_exp2(fmaf(V[k], zan, zbn)));         \
        P[k]  = fmaf(A_p, P[k],  B_p * sp);                                    \
        Q[k]  = fmaf(A_q, Q[k],  B_q * sq);                                    \
        E[k]  = fmaf(A_e, E[k],  B_e * se);                                    \
        F[k]  = fmaf(A_f, F[k],  B_f * sf);                                    \
        NN[k] = fmaf(A_n, NN[k], B_n * sn);                                    \
        ST(oV, bo[k]) = V[k];  ST(oP, bo[k]) = P[k];                           \
        ST(oQ, bo[k]) = Q[k];  ST(oN, bo[k]) = NN[k];                          \
        ST(oE, bo[k]) = E[k];  ST(oF, bo[k]) = F[k];                           \
        ST(oC, bo[k]) = C[k];                                                  \
        bo[k] += BSTEP;                                                        \
    }

    // depth-4 prefetch pipeline per neuron stream
    float buf[KN][4];
#pragma unroll
    for (int j = 0; j < 4; ++j)
#pragma unroll
        for (int k = 0; k < KN; ++k)
            buf[k][j] = LD(i0[k] + (unsigned)j * ISTEP);

    // 125 blocks of 4 steps; prefetch row index clamped (uniform scalar min)
    for (int t0 = 0; t0 < TSTEPS; t0 += 4) {
        float nbuf[KN][4];
#pragma unroll
        for (int j = 0; j < 4; ++j) {
            int tt = t0 + 4 + j;
            tt = tt < TSTEPS ? tt : TSTEPS - 1;   // uniform clamp; dummy unused
            const unsigned ro = (unsigned)tt * ISTEP;
#pragma unroll
            for (int k = 0; k < KN; ++k)
                nbuf[k][j] = LD(i0[k] + ro);
        }
#pragma unroll
        for (int j = 0; j < 4; ++j) {
#pragma unroll
            for (int k = 0; k < KN; ++k)
                HH_STEP(k, buf[k][j]);
        }
#pragma unroll
        for (int j = 0; j < 4; ++j)
#pragma unroll
            for (int k = 0; k < KN; ++k)
                buf[k][j] = nbuf[k][j];
    }

#undef HH_STEP
#undef LD
#undef ST
}

extern "C" void kernel_launch(void* const* d_in, const int* in_sizes, int n_in,
                              void* d_out, int out_size, void* d_ws, size_t ws_size,
                              hipStream_t stream) {
    const float* i_inj  = (const float*)d_in[0];
    const float* x0     = (const float*)d_in[1];
    const float* params = (const float*)d_in[2];
    float* out = (float*)d_out;

    const int block = 64;
    const int grid  = (NT + block - 1) / block;   // 79 blocks of 64 = 5056 threads
    hipLaunchKernelGGL(hh_kernel, dim3(grid), dim3(block), 0, stream,
                       i_inj, x0, params, out);
}